// Round 12
// baseline (276.386 us; speedup 1.0000x reference)
//
#include <hip/hip_runtime.h>
#include <hip/hip_bf16.h>
#include <cstdint>

// ============================================================================
// ScaledDotAttention: out = softmax((Q Wq^T + bq)(K Wk^T + bk)^T / 8) @ V
// B=8, N=4096, DK=512, DM=64.
// R12: single-barrier pipelined step.
//      - 16 waves @ 4/SIMD (1024 thr), vt dbuf via global_load_lds
//      - pk NEVER in LDS: per-wave A-fragments loaded global->reg, issued
//        pre-barrier (land during barrier + next-step QKT)
//      - P double-buffered (write p[pb^1] while PV reads p[pb]) -> ONE
//        lgkm0+vmcnt0 barrier per step; vmcnt(0) is free (DMA issued a full
//        step earlier) and makes the vt handoff airtight cross-wave.
//      - LDS = 2x64K vt + 2x16K P = 163840 B exactly; lsum aliased into p[0].
// ============================================================================

#define DEVINL __device__ __forceinline__

using f32x4  = __attribute__((ext_vector_type(4)))  float;
using bf16x8 = __attribute__((ext_vector_type(8)))  short;
using bf16x4 = __attribute__((ext_vector_type(4)))  short;

constexpr int BATCH = 8;
constexpr int N     = 4096;
constexpr int DK    = 512;
constexpr int DM    = 64;
constexpr int KVB   = 64;
constexpr int QB    = 128;
constexpr int STEPS = N / KVB;       // 64
constexpr int PBUF  = QB * KVB;      // shorts per P buffer (8192)

#define PQ_SCALE 0.18033688011112042f
#define FM 10.0f

DEVINL short cvt_bf16(float x) {
  uint32_t u = __float_as_uint(x);
  uint32_t r = u + 0x7fffu + ((u >> 16) & 1u);
  return (short)(r >> 16);
}

DEVINL uint32_t cvtpk(float lo, float hi) {
  uint32_t r;
  asm("v_cvt_pk_bf16_f32 %0, %1, %2" : "=v"(r) : "v"(lo), "v"(hi));
  return r;
}

DEVINL void async16(void* lds, const void* g) {
  __builtin_amdgcn_global_load_lds(
      (const __attribute__((address_space(1))) uint32_t*)(uintptr_t)g,
      (__attribute__((address_space(3))) uint32_t*)(uint32_t)(uintptr_t)lds,
      16, 0, 0);
}

DEVINL f32x4 mfma16(bf16x8 a, bf16x8 b, f32x4 c) {
  return __builtin_amdgcn_mfma_f32_16x16x32_bf16(a, b, c, 0, 0, 0);
}

#define LGKM0_BAR() do { \
  asm volatile("s_waitcnt lgkmcnt(0)" ::: "memory"); \
  __builtin_amdgcn_s_barrier(); \
} while (0)

// ---------------------------------------------------------------------------
__global__ __launch_bounds__(256) void wconv_kernel(
    const float* __restrict__ Wk, const float* __restrict__ Wq,
    short* __restrict__ WkB, short* __restrict__ WqB) {
  int i = blockIdx.x * 256 + threadIdx.x;
  WkB[i] = cvt_bf16(Wk[i]);
  WqB[i] = cvt_bf16(Wq[i]);
}

// ---------------------------------------------------------------------------
__global__ __launch_bounds__(256) void vtrans_kernel(
    const float* __restrict__ V, short* __restrict__ Vt) {
  int bb = blockIdx.x;
  int b  = bb >> 9;
  int nt = (bb >> 3) & 63;
  int dt = bb & 7;
  int n0 = nt * 64, d0 = dt * 64;
  __shared__ short t_lds[64][80];
  int tid = threadIdx.x;
#pragma unroll
  for (int it = 0; it < 4; ++it) {
    int idx = it * 256 + tid;
    int row = idx >> 4;
    int c4  = idx & 15;
    f32x4 v = *(const f32x4*)&V[((size_t)b * N + n0 + row) * DK + d0 + c4 * 4];
#pragma unroll
    for (int j = 0; j < 4; ++j) t_lds[c4 * 4 + j][row] = cvt_bf16(v[j]);
  }
  __syncthreads();
#pragma unroll
  for (int it = 0; it < 2; ++it) {
    int idx = it * 256 + tid;
    int rd = idx >> 3;
    int ck = idx & 7;
    bf16x8 vv = *(const bf16x8*)&t_lds[rd][ck * 8];
    *(bf16x8*)&Vt[((size_t)b * DK + d0 + rd) * N + n0 + ck * 8] = vv;
  }
}

// ---------------------------------------------------------------------------
__global__ __launch_bounds__(512, 2) void proj_kernel(
    const float* __restrict__ Q, const float* __restrict__ K,
    const short* __restrict__ WqB, const short* __restrict__ WkB,
    const float* __restrict__ bq, const float* __restrict__ bk,
    short* __restrict__ pq, short* __restrict__ pk) {
  bool isK = blockIdx.x >= 256;
  const float* X    = isK ? K : Q;
  const short* W    = isK ? WkB : WqB;
  const float* bias = isK ? bk : bq;
  short* P          = isK ? pk : pq;
  float sc          = isK ? 1.0f : PQ_SCALE;
  int rb = (blockIdx.x & 255) * 128;

  __shared__ short x_lds[128 * 512];
  int tid = threadIdx.x, w = tid >> 6, lane = tid & 63, g = lane >> 4, c = lane & 15;

#pragma unroll
  for (int it = 0; it < 32; ++it) {
    int idx4 = it * 512 + tid;
    int row  = idx4 >> 7;
    int col  = (idx4 & 127) * 4;
    f32x4 v = *(const f32x4*)&X[((size_t)rb + row) * DK + col];
    bf16x4 hb;
#pragma unroll
    for (int j = 0; j < 4; ++j) hb[j] = cvt_bf16(v[j]);
    int scz = (col >> 3) ^ (row & 7);
    *(bf16x4*)&x_lds[row * 512 + scz * 8 + ((col >> 2) & 1) * 4] = hb;
  }
  __syncthreads();

  f32x4 o[4];
#pragma unroll
  for (int mt = 0; mt < 4; ++mt) o[mt] = f32x4{0.f, 0.f, 0.f, 0.f};
  int arow = w * 16 + c;
#pragma unroll
  for (int ks = 0; ks < 16; ++ks) {
    int scz = (ks * 4 + g) ^ (arow & 7);
    bf16x8 a = *(const bf16x8*)&x_lds[arow * 512 + scz * 8];
#pragma unroll
    for (int mt = 0; mt < 4; ++mt) {
      bf16x8 bfr = *(const bf16x8*)&W[(size_t)(mt * 16 + c) * DK + ks * 32 + g * 8];
      o[mt] = mfma16(a, bfr, o[mt]);
    }
  }
#pragma unroll
  for (int mt = 0; mt < 4; ++mt) {
    float bb = bias[mt * 16 + c];
#pragma unroll
    for (int r = 0; r < 4; ++r) {
      int row = rb + w * 16 + g * 4 + r;
      P[(size_t)row * DM + mt * 16 + c] = cvt_bf16((o[mt][r] + bb) * sc);
    }
  }
}

// ---------------------------------------------------------------------------
__global__ __launch_bounds__(1024, 4) void flash_kernel(
    const short* __restrict__ pq, const short* __restrict__ pk,
    const short* __restrict__ vt, float* __restrict__ out) {
  int b  = blockIdx.x & 7;             // batch -> XCD (L2-local vt/pk)
  int qt = blockIdx.x >> 3;            // 0..31
  int q0 = qt * QB;

  int tid = threadIdx.x, w = tid >> 6, lane = tid & 63, g = lane >> 4, c = lane & 15;
  int cs = c & 7;
  int qg = w & 7, kqh = w >> 3;        // qkt role: 16 q x 32 keys
  int qrow = qg * 16 + c;
  int vh = w >> 3, vs = w & 7;         // pv role: 64 vcols x 64 q

  __shared__ short vt_lds[2][DK * KVB];   // 128KB dbuf
  __shared__ short p_lds[2][PBUF];        //  32KB dbuf

  // pv LDS pointers (buffer 0 bases; +PBUF / +DK*KVB for buffer 1)
  const short* pfr0 = &p_lds[0][(vh * 64 + c) * 64 + ((g ^ cs) * 8)];
  const short* pfr1 = &p_lds[0][(vh * 64 + c) * 64 + (((4 + g) ^ cs) * 8)];
  const short* vfA0 = &vt_lds[0][(vs * 64 + c) * 64 + ((g ^ cs) * 8)];
  const short* vfA1 = &vt_lds[0][(vs * 64 + c) * 64 + (((4 + g) ^ cs) * 8)];
  // P write pointers (buffer 0 bases)
  short* pw0 = &p_lds[0][qrow * 64 + (((kqh * 4 + 0 + (g >> 1)) ^ cs) * 8) + (g & 1) * 4];
  short* pw1 = &p_lds[0][qrow * 64 + (((kqh * 4 + 2 + (g >> 1)) ^ cs) * 8) + (g & 1) * 4];

  // vt staging: 4 x async16 per thread
  const short* vt_base = vt + (size_t)b * DK * N;
  int tr = tid >> 3, tc = tid & 7;
  int vt_vo[4];
#pragma unroll
  for (int r = 0; r < 4; ++r)
    vt_vo[r] = (r * 128 + tr) * N + ((tc ^ (tr & 7)) * 8);
  short* vt_dst0 = &vt_lds[0][w * 512];
  short* vt_dst1 = &vt_lds[1][w * 512];

  // pk fragments: global->reg, per-wave (rows kqh*32 + s*16 + c, col half g)
  const short* pk_src = pk + (size_t)b * N * DM + (size_t)(kqh * 32 + c) * DM + g * 8;

  // pq fragments
  const short* pq_row = pq + ((size_t)b * N + q0 + qrow) * DM;
  bf16x8 qf0 = *(const bf16x8*)(pq_row + g * 8);
  bf16x8 qf1 = *(const bf16x8*)(pq_row + 32 + g * 8);

  f32x4 acc[4][4];
#pragma unroll
  for (int i = 0; i < 4; ++i)
#pragma unroll
    for (int j = 0; j < 4; ++j) acc[i][j] = f32x4{0.f, 0.f, 0.f, 0.f};

  float lp = 0.f;
  uint32_t pbu[4];
  bf16x8 pkf[4];                       // [s*2+h]

  // ========================= prolog ========================================
  pkf[0] = *(const bf16x8*)(pk_src);          // pk(0)
  pkf[1] = *(const bf16x8*)(pk_src + 32);
  pkf[2] = *(const bf16x8*)(pk_src + 1024);
  pkf[3] = *(const bf16x8*)(pk_src + 1056);
  pk_src += KVB * DM;
#pragma unroll
  for (int r = 0; r < 4; ++r)
    async16((void*)(vt_dst0 + r * 8192), (const void*)(vt_base + vt_vo[r]));
  vt_base += KVB;
  __syncthreads();                     // full drain: vt(0) landed

  // S(0) -> P(0) into p[0]
#pragma unroll
  for (int s = 0; s < 2; ++s) {
    f32x4 d = f32x4{-FM, -FM, -FM, -FM};
    d = mfma16(pkf[s * 2], qf0, d);
    d = mfma16(pkf[s * 2 + 1], qf1, d);
    float p0 = exp2f(d[0]), p1 = exp2f(d[1]);
    float p2 = exp2f(d[2]), p3 = exp2f(d[3]);
    lp += (p0 + p1) + (p2 + p3);
    pbu[s * 2]     = cvtpk(p0, p1);
    pbu[s * 2 + 1] = cvtpk(p2, p3);
  }
  *(uint2*)pw0 = uint2{pbu[0], pbu[1]};
  *(uint2*)pw1 = uint2{pbu[2], pbu[3]};
  pkf[0] = *(const bf16x8*)(pk_src);          // pk(1)
  pkf[1] = *(const bf16x8*)(pk_src + 32);
  pkf[2] = *(const bf16x8*)(pk_src + 1024);
  pkf[3] = *(const bf16x8*)(pk_src + 1056);
  pk_src += KVB * DM;
  LGKM0_BAR();                         // P(0) visible
  __builtin_amdgcn_sched_barrier(0);

  // ========================= main loop ====================================
  // step t: stage vt(t+1); QKT(t+1) from pkf regs; P(t+1)->p[pb^1];
  //         PV(t) from p[pb]+vt[vb]; vmcnt(0); load pk(t+2); lgkm0+barrier.
  for (int t = 0; t < STEPS - 1; ++t) {
    int vb = t & 1;
    short* vdst = vb ? vt_dst0 : vt_dst1;
#pragma unroll
    for (int r = 0; r < 4; ++r)
      async16((void*)(vdst + r * 8192), (const void*)(vt_base + vt_vo[r]));
    vt_base += KVB;
    __builtin_amdgcn_sched_barrier(0);

    // ---- QKT(t+1): pure register MFMAs (pkf loaded pre-barrier last step) --
#pragma unroll
    for (int s = 0; s < 2; ++s) {
      f32x4 d = f32x4{-FM, -FM, -FM, -FM};
      d = mfma16(pkf[s * 2], qf0, d);
      d = mfma16(pkf[s * 2 + 1], qf1, d);
      float p0 = exp2f(d[0]), p1 = exp2f(d[1]);
      float p2 = exp2f(d[2]), p3 = exp2f(d[3]);
      lp += (p0 + p1) + (p2 + p3);
      pbu[s * 2]     = cvtpk(p0, p1);
      pbu[s * 2 + 1] = cvtpk(p2, p3);
    }
    // publish P(t+1) into the buffer NOT being read this step
    {
      int po = (vb ^ 1) * PBUF;
      *(uint2*)(pw0 + po) = uint2{pbu[0], pbu[1]};
      *(uint2*)(pw1 + po) = uint2{pbu[2], pbu[3]};
    }

    // ---- PV(t): 16 LDS reads + 32 MFMAs ----
    {
      int po = vb * PBUF;
      int vo = vb * (DK * KVB);
      const short* pf0 = pfr0 + po;
      const short* pf1 = pfr1 + po;
      const short* vf0 = vfA0 + vo;
      const short* vf1 = vfA1 + vo;
      __builtin_amdgcn_s_setprio(1);
      bf16x8 vf[4];
#pragma unroll
      for (int i = 0; i < 4; ++i) vf[i] = *(const bf16x8*)(vf0 + i * 1024);
#pragma unroll
      for (int j = 0; j < 4; ++j) {
        bf16x8 pf = *(const bf16x8*)(pf0 + j * 1024);
#pragma unroll
        for (int i = 0; i < 4; ++i) acc[i][j] = mfma16(vf[i], pf, acc[i][j]);
      }
#pragma unroll
      for (int i = 0; i < 4; ++i) vf[i] = *(const bf16x8*)(vf1 + i * 1024);
#pragma unroll
      for (int j = 0; j < 4; ++j) {
        bf16x8 pf = *(const bf16x8*)(pf1 + j * 1024);
#pragma unroll
        for (int i = 0; i < 4; ++i) acc[i][j] = mfma16(vf[i], pf, acc[i][j]);
      }
      __builtin_amdgcn_s_setprio(0);
    }

    // ---- step bottom: drain DMA (free), prefetch pk(t+2), one barrier ----
    asm volatile("s_waitcnt vmcnt(0)" ::: "memory");
    if (t < STEPS - 2) {
      pkf[0] = *(const bf16x8*)(pk_src);
      pkf[1] = *(const bf16x8*)(pk_src + 32);
      pkf[2] = *(const bf16x8*)(pk_src + 1024);
      pkf[3] = *(const bf16x8*)(pk_src + 1056);
      pk_src += KVB * DM;
    }
    LGKM0_BAR();
    __builtin_amdgcn_sched_barrier(0);
  }

  // ========================= epilog: PV(last) ==============================
  {
    int vb = (STEPS - 1) & 1;          // = 1
    int po = vb * PBUF;
    int vo = vb * (DK * KVB);
    const short* pf0 = pfr0 + po;
    const short* pf1 = pfr1 + po;
    const short* vf0 = vfA0 + vo;
    const short* vf1 = vfA1 + vo;
    bf16x8 vf[4];
#pragma unroll
    for (int i = 0; i < 4; ++i) vf[i] = *(const bf16x8*)(vf0 + i * 1024);
#pragma unroll
    for (int j = 0; j < 4; ++j) {
      bf16x8 pf = *(const bf16x8*)(pf0 + j * 1024);
#pragma unroll
      for (int i = 0; i < 4; ++i) acc[i][j] = mfma16(vf[i], pf, acc[i][j]);
    }
#pragma unroll
    for (int i = 0; i < 4; ++i) vf[i] = *(const bf16x8*)(vf1 + i * 1024);
#pragma unroll
    for (int j = 0; j < 4; ++j) {
      bf16x8 pf = *(const bf16x8*)(pf1 + j * 1024);
#pragma unroll
      for (int i = 0; i < 4; ++i) acc[i][j] = mfma16(vf[i], pf, acc[i][j]);
    }
  }

  // l reduce: lsum aliased into p_lds[0] (PV(63) read p[1]; p[0] free)
  float* lsum2 = (float*)&p_lds[0][0];   // [2][QB] floats = 1KB
  lp += __shfl_xor(lp, 16);
  lp += __shfl_xor(lp, 32);
  if (g == 0) lsum2[kqh * QB + qrow] = lp;
  LGKM0_BAR();

  float* out_b = out + (size_t)b * N * DK;
#pragma unroll
  for (int j = 0; j < 4; ++j) {
    int qq = vh * 64 + j * 16 + c;
    float rl = 1.f / (lsum2[qq] + lsum2[QB + qq]);
    int q = q0 + qq;
#pragma unroll
    for (int i = 0; i < 4; ++i) {
      f32x4 o = acc[i][j];
      o[0] *= rl; o[1] *= rl; o[2] *= rl; o[3] *= rl;
      *(f32x4*)&out_b[(size_t)q * DK + vs * 64 + i * 16 + g * 4] = o;
    }
  }
}

// ---------------------------------------------------------------------------
extern "C" void kernel_launch(void* const* d_in, const int* in_sizes, int n_in,
                              void* d_out, int out_size, void* d_ws, size_t ws_size,
                              hipStream_t stream) {
  (void)in_sizes; (void)n_in; (void)out_size; (void)ws_size;
  const float* K  = (const float*)d_in[0];
  const float* Q  = (const float*)d_in[1];
  const float* V  = (const float*)d_in[2];
  const float* Wk = (const float*)d_in[3];
  const float* bk = (const float*)d_in[4];
  const float* Wq = (const float*)d_in[5];
  const float* bq = (const float*)d_in[6];
  float* out = (float*)d_out;

  char* ws = (char*)d_ws;
  short* pq  = (short*)(ws + 0);
  short* pk  = (short*)(ws + ((size_t)4 << 20));
  short* vt  = (short*)(ws + ((size_t)8 << 20));
  short* WqB = (short*)(ws + ((size_t)40 << 20));
  short* WkB = (short*)(ws + ((size_t)40 << 20) + 64 * 512 * 2);

  hipLaunchKernelGGL(wconv_kernel,  dim3(128),  dim3(256), 0, stream, Wk, Wq, WkB, WqB);
  hipLaunchKernelGGL(vtrans_kernel, dim3(4096), dim3(256), 0, stream, V, vt);
  hipLaunchKernelGGL(proj_kernel,   dim3(512),  dim3(512), 0, stream, Q, K, WqB, WkB, bq, bk, pq, pk);
  hipLaunchKernelGGL(flash_kernel,  dim3(256),  dim3(1024), 0, stream, pq, pk, vt, out);
}

// Round 13
// 259.857 us; speedup vs baseline: 1.0636x; 1.0636x over previous
//
#include <hip/hip_runtime.h>
#include <hip/hip_bf16.h>
#include <cstdint>

// ============================================================================
// ScaledDotAttention: out = softmax((Q Wq^T + bq)(K Wk^T + bk)^T / 8) @ V
// B=8, N=4096, DK=512, DM=64.
// R13: R11 base (16 waves @ 4/SIMD, vt dbuf global_load_lds, vmcnt(5),
//      reg-staged pk pinned before DMAs, fixed-max exp2 softmax, two lgkm
//      barriers) + kqh role STAGGER: each SIMD hosts kqh={0,0,1,1}; kqh=0
//      waves run QKT->PV, kqh=1 run PV->QKT, spreading LDS-read and MFMA
//      bursts across the step (attacks the 36% LDS-idle overlap gap).
// ============================================================================

#define DEVINL __device__ __forceinline__

using f32x4  = __attribute__((ext_vector_type(4)))  float;
using bf16x8 = __attribute__((ext_vector_type(8)))  short;
using bf16x4 = __attribute__((ext_vector_type(4)))  short;

constexpr int BATCH = 8;
constexpr int N     = 4096;
constexpr int DK    = 512;
constexpr int DM    = 64;
constexpr int KVB   = 64;
constexpr int QB    = 128;
constexpr int STEPS = N / KVB;       // 64

#define PQ_SCALE 0.18033688011112042f
#define FM 10.0f

DEVINL short cvt_bf16(float x) {
  uint32_t u = __float_as_uint(x);
  uint32_t r = u + 0x7fffu + ((u >> 16) & 1u);
  return (short)(r >> 16);
}

DEVINL uint32_t cvtpk(float lo, float hi) {
  uint32_t r;
  asm("v_cvt_pk_bf16_f32 %0, %1, %2" : "=v"(r) : "v"(lo), "v"(hi));
  return r;
}

DEVINL void async16(void* lds, const void* g) {
  __builtin_amdgcn_global_load_lds(
      (const __attribute__((address_space(1))) uint32_t*)(uintptr_t)g,
      (__attribute__((address_space(3))) uint32_t*)(uint32_t)(uintptr_t)lds,
      16, 0, 0);
}

DEVINL f32x4 mfma16(bf16x8 a, bf16x8 b, f32x4 c) {
  return __builtin_amdgcn_mfma_f32_16x16x32_bf16(a, b, c, 0, 0, 0);
}

#define LGKM0_BAR() do { \
  asm volatile("s_waitcnt lgkmcnt(0)" ::: "memory"); \
  __builtin_amdgcn_s_barrier(); \
} while (0)

// ---------------------------------------------------------------------------
__global__ __launch_bounds__(256) void wconv_kernel(
    const float* __restrict__ Wk, const float* __restrict__ Wq,
    short* __restrict__ WkB, short* __restrict__ WqB) {
  int i = blockIdx.x * 256 + threadIdx.x;
  WkB[i] = cvt_bf16(Wk[i]);
  WqB[i] = cvt_bf16(Wq[i]);
}

// ---------------------------------------------------------------------------
__global__ __launch_bounds__(256) void vtrans_kernel(
    const float* __restrict__ V, short* __restrict__ Vt) {
  int bb = blockIdx.x;
  int b  = bb >> 9;
  int nt = (bb >> 3) & 63;
  int dt = bb & 7;
  int n0 = nt * 64, d0 = dt * 64;
  __shared__ short t_lds[64][80];
  int tid = threadIdx.x;
#pragma unroll
  for (int it = 0; it < 4; ++it) {
    int idx = it * 256 + tid;
    int row = idx >> 4;
    int c4  = idx & 15;
    f32x4 v = *(const f32x4*)&V[((size_t)b * N + n0 + row) * DK + d0 + c4 * 4];
#pragma unroll
    for (int j = 0; j < 4; ++j) t_lds[c4 * 4 + j][row] = cvt_bf16(v[j]);
  }
  __syncthreads();
#pragma unroll
  for (int it = 0; it < 2; ++it) {
    int idx = it * 256 + tid;
    int rd = idx >> 3;
    int ck = idx & 7;
    bf16x8 vv = *(const bf16x8*)&t_lds[rd][ck * 8];
    *(bf16x8*)&Vt[((size_t)b * DK + d0 + rd) * N + n0 + ck * 8] = vv;
  }
}

// ---------------------------------------------------------------------------
__global__ __launch_bounds__(512, 2) void proj_kernel(
    const float* __restrict__ Q, const float* __restrict__ K,
    const short* __restrict__ WqB, const short* __restrict__ WkB,
    const float* __restrict__ bq, const float* __restrict__ bk,
    short* __restrict__ pq, short* __restrict__ pk) {
  bool isK = blockIdx.x >= 256;
  const float* X    = isK ? K : Q;
  const short* W    = isK ? WkB : WqB;
  const float* bias = isK ? bk : bq;
  short* P          = isK ? pk : pq;
  float sc          = isK ? 1.0f : PQ_SCALE;
  int rb = (blockIdx.x & 255) * 128;

  __shared__ short x_lds[128 * 512];
  int tid = threadIdx.x, w = tid >> 6, lane = tid & 63, g = lane >> 4, c = lane & 15;

#pragma unroll
  for (int it = 0; it < 32; ++it) {
    int idx4 = it * 512 + tid;
    int row  = idx4 >> 7;
    int col  = (idx4 & 127) * 4;
    f32x4 v = *(const f32x4*)&X[((size_t)rb + row) * DK + col];
    bf16x4 hb;
#pragma unroll
    for (int j = 0; j < 4; ++j) hb[j] = cvt_bf16(v[j]);
    int scz = (col >> 3) ^ (row & 7);
    *(bf16x4*)&x_lds[row * 512 + scz * 8 + ((col >> 2) & 1) * 4] = hb;
  }
  __syncthreads();

  f32x4 o[4];
#pragma unroll
  for (int mt = 0; mt < 4; ++mt) o[mt] = f32x4{0.f, 0.f, 0.f, 0.f};
  int arow = w * 16 + c;
#pragma unroll
  for (int ks = 0; ks < 16; ++ks) {
    int scz = (ks * 4 + g) ^ (arow & 7);
    bf16x8 a = *(const bf16x8*)&x_lds[arow * 512 + scz * 8];
#pragma unroll
    for (int mt = 0; mt < 4; ++mt) {
      bf16x8 bfr = *(const bf16x8*)&W[(size_t)(mt * 16 + c) * DK + ks * 32 + g * 8];
      o[mt] = mfma16(a, bfr, o[mt]);
    }
  }
#pragma unroll
  for (int mt = 0; mt < 4; ++mt) {
    float bb = bias[mt * 16 + c];
#pragma unroll
    for (int r = 0; r < 4; ++r) {
      int row = rb + w * 16 + g * 4 + r;
      P[(size_t)row * DM + mt * 16 + c] = cvt_bf16((o[mt][r] + bb) * sc);
    }
  }
}

// ---------------------------------------------------------------------------
__global__ __launch_bounds__(1024, 4) void flash_kernel(
    const short* __restrict__ pq, const short* __restrict__ pk,
    const short* __restrict__ vt, float* __restrict__ out) {
  int b  = blockIdx.x & 7;             // batch -> XCD (L2-local vt/pk)
  int qt = blockIdx.x >> 3;            // 0..31
  int q0 = qt * QB;

  int tid = threadIdx.x, w = tid >> 6, lane = tid & 63, g = lane >> 4, c = lane & 15;
  int cs = c & 7;
  int qg = w & 7, kqh = w >> 3;        // qkt role: 16 q x 32 keys
  int qrow = qg * 16 + c;
  int vh = w >> 3, vs = w & 7;         // pv role: 64 vcols x 64 q

  __shared__ short vt_lds[2][DK * KVB];         // 128KB dbuf
  __shared__ short pk_lds[KVB * DM];            //  8KB
  __shared__ short p_lds[QB * KVB];             // 16KB
  __shared__ float lsum2[2][QB];

  // qkt LDS pointers
  const short* pkr0 = pk_lds + (kqh * 32 + c) * 64 + ((g ^ cs) * 8);
  const short* pkr1 = pk_lds + (kqh * 32 + c) * 64 + (((4 + g) ^ cs) * 8);
  short* pw0 = p_lds + qrow * 64 + (((kqh * 4 + 0 + (g >> 1)) ^ cs) * 8) + (g & 1) * 4;
  short* pw1 = p_lds + qrow * 64 + (((kqh * 4 + 2 + (g >> 1)) ^ cs) * 8) + (g & 1) * 4;

  // pv LDS pointers
  const short* pfr0 = p_lds + (vh * 64 + c) * 64 + ((g ^ cs) * 8);
  const short* pfr1 = p_lds + (vh * 64 + c) * 64 + (((4 + g) ^ cs) * 8);
  const short* vfA0 = &vt_lds[0][(vs * 64 + c) * 64 + ((g ^ cs) * 8)];
  const short* vfA1 = &vt_lds[0][(vs * 64 + c) * 64 + (((4 + g) ^ cs) * 8)];
  const short* vfB0 = vfA0 + DK * KVB;
  const short* vfB1 = vfA1 + DK * KVB;

  // vt staging: 4 x async16 per thread
  const short* vt_base = vt + (size_t)b * DK * N;
  int tr = tid >> 3, tc = tid & 7;
  int vt_vo[4];
#pragma unroll
  for (int r = 0; r < 4; ++r)
    vt_vo[r] = (r * 128 + tr) * N + ((tc ^ (tr & 7)) * 8);
  short* vt_dst0 = &vt_lds[0][w * 512];
  short* vt_dst1 = &vt_lds[1][w * 512];

  // pk reg-staging: 8B per thread
  const short* pk_base = pk + (size_t)b * N * DM;
  {
    int prow = tid >> 4, h = tid & 15;
    pk_base += prow * 64 + (((h >> 1) ^ (prow & 7)) * 8) + (h & 1) * 4;
  }
  short* pk_wr = pk_lds + tid * 4;
  bf16x4 pkreg;

  // pq fragments
  const short* pq_row = pq + ((size_t)b * N + q0 + qrow) * DM;
  bf16x8 qf0 = *(const bf16x8*)(pq_row + g * 8);
  bf16x8 qf1 = *(const bf16x8*)(pq_row + 32 + g * 8);

  f32x4 acc[4][4];
#pragma unroll
  for (int i = 0; i < 4; ++i)
#pragma unroll
    for (int j = 0; j < 4; ++j) acc[i][j] = f32x4{0.f, 0.f, 0.f, 0.f};

  float lp = 0.f;
  uint32_t pbu[4];

  // ========================= prolog ========================================
#pragma unroll
  for (int r = 0; r < 4; ++r)
    async16((void*)(vt_dst0 + r * 8192), (const void*)(vt_base + vt_vo[r]));
  vt_base += KVB;
  pkreg = *(const bf16x4*)pk_base;     // pk(0)
  pk_base += KVB * DM;
  *(bf16x4*)pk_wr = pkreg;
  __syncthreads();                     // full drain: vt(0)+pk(0) visible

  // S(0)
#pragma unroll
  for (int s = 0; s < 2; ++s) {
    bf16x8 a0 = *(const bf16x8*)(pkr0 + s * 1024);
    bf16x8 a1 = *(const bf16x8*)(pkr1 + s * 1024);
    f32x4 d = f32x4{-FM, -FM, -FM, -FM};
    d = mfma16(a0, qf0, d);
    d = mfma16(a1, qf1, d);
    float p0 = exp2f(d[0]), p1 = exp2f(d[1]);
    float p2 = exp2f(d[2]), p3 = exp2f(d[3]);
    lp += (p0 + p1) + (p2 + p3);
    pbu[s * 2]     = cvtpk(p0, p1);
    pbu[s * 2 + 1] = cvtpk(p2, p3);
  }
  pkreg = *(const bf16x4*)pk_base;     // pk(1)
  pk_base += KVB * DM;
  LGKM0_BAR();                         // all pk(0) reads done
  *(uint2*)pw0 = uint2{pbu[0], pbu[1]};
  *(uint2*)pw1 = uint2{pbu[2], pbu[3]};
  *(bf16x4*)pk_wr = pkreg;
  LGKM0_BAR();                         // P(0)+pk(1) visible
  __builtin_amdgcn_sched_barrier(0);

  // ========================= main loop: PV(t) + QKT(t+1) ===================
  for (int t = 0; t < STEPS - 1; ++t) {
    int vb = t & 1;
    // pk(t+2) FIRST, pinned before the vt DMAs
    pkreg = *(const bf16x4*)pk_base;
    pk_base += KVB * DM;
    __builtin_amdgcn_sched_barrier(0);
    short* vdst = vb ? vt_dst0 : vt_dst1;
#pragma unroll
    for (int r = 0; r < 4; ++r)
      async16((void*)(vdst + r * 8192), (const void*)(vt_base + vt_vo[r]));
    vt_base += KVB;
    // queue: [vt(t):4, pk(t+2):1, vt(t+1):4] -> drain exactly vt(t)
    asm volatile("s_waitcnt vmcnt(5)" ::: "memory");
    __builtin_amdgcn_sched_barrier(0);

    const short* vf0 = vb ? vfB0 : vfA0;
    const short* vf1 = vb ? vfB1 : vfA1;

    if (kqh == 0) {
      // ---- QKT(t+1) then PV(t) ----
#pragma unroll
      for (int s = 0; s < 2; ++s) {
        bf16x8 a0 = *(const bf16x8*)(pkr0 + s * 1024);
        bf16x8 a1 = *(const bf16x8*)(pkr1 + s * 1024);
        f32x4 d = f32x4{-FM, -FM, -FM, -FM};
        d = mfma16(a0, qf0, d);
        d = mfma16(a1, qf1, d);
        float p0 = exp2f(d[0]), p1 = exp2f(d[1]);
        float p2 = exp2f(d[2]), p3 = exp2f(d[3]);
        lp += (p0 + p1) + (p2 + p3);
        pbu[s * 2]     = cvtpk(p0, p1);
        pbu[s * 2 + 1] = cvtpk(p2, p3);
      }
      __builtin_amdgcn_s_setprio(1);
      {
        bf16x8 vf[4];
#pragma unroll
        for (int i = 0; i < 4; ++i) vf[i] = *(const bf16x8*)(vf0 + i * 1024);
#pragma unroll
        for (int j = 0; j < 4; ++j) {
          bf16x8 pf = *(const bf16x8*)(pfr0 + j * 1024);
#pragma unroll
          for (int i = 0; i < 4; ++i) acc[i][j] = mfma16(vf[i], pf, acc[i][j]);
        }
#pragma unroll
        for (int i = 0; i < 4; ++i) vf[i] = *(const bf16x8*)(vf1 + i * 1024);
#pragma unroll
        for (int j = 0; j < 4; ++j) {
          bf16x8 pf = *(const bf16x8*)(pfr1 + j * 1024);
#pragma unroll
          for (int i = 0; i < 4; ++i) acc[i][j] = mfma16(vf[i], pf, acc[i][j]);
        }
      }
      __builtin_amdgcn_s_setprio(0);
    } else {
      // ---- PV(t) then QKT(t+1) ----
      __builtin_amdgcn_s_setprio(1);
      {
        bf16x8 vf[4];
#pragma unroll
        for (int i = 0; i < 4; ++i) vf[i] = *(const bf16x8*)(vf0 + i * 1024);
#pragma unroll
        for (int j = 0; j < 4; ++j) {
          bf16x8 pf = *(const bf16x8*)(pfr0 + j * 1024);
#pragma unroll
          for (int i = 0; i < 4; ++i) acc[i][j] = mfma16(vf[i], pf, acc[i][j]);
        }
#pragma unroll
        for (int i = 0; i < 4; ++i) vf[i] = *(const bf16x8*)(vf1 + i * 1024);
#pragma unroll
        for (int j = 0; j < 4; ++j) {
          bf16x8 pf = *(const bf16x8*)(pfr1 + j * 1024);
#pragma unroll
          for (int i = 0; i < 4; ++i) acc[i][j] = mfma16(vf[i], pf, acc[i][j]);
        }
      }
      __builtin_amdgcn_s_setprio(0);
#pragma unroll
      for (int s = 0; s < 2; ++s) {
        bf16x8 a0 = *(const bf16x8*)(pkr0 + s * 1024);
        bf16x8 a1 = *(const bf16x8*)(pkr1 + s * 1024);
        f32x4 d = f32x4{-FM, -FM, -FM, -FM};
        d = mfma16(a0, qf0, d);
        d = mfma16(a1, qf1, d);
        float p0 = exp2f(d[0]), p1 = exp2f(d[1]);
        float p2 = exp2f(d[2]), p3 = exp2f(d[3]);
        lp += (p0 + p1) + (p2 + p3);
        pbu[s * 2]     = cvtpk(p0, p1);
        pbu[s * 2 + 1] = cvtpk(p2, p3);
      }
    }

    LGKM0_BAR();                       // barrier 1: all p/pk LDS reads done
    __builtin_amdgcn_sched_barrier(0);

    if (t < STEPS - 2) *(bf16x4*)pk_wr = pkreg;  // waits only pk (vmcnt~4)
    *(uint2*)pw0 = uint2{pbu[0], pbu[1]};
    *(uint2*)pw1 = uint2{pbu[2], pbu[3]};
    LGKM0_BAR();                       // barrier 2: writes visible
    __builtin_amdgcn_sched_barrier(0);
  }

  // ========================= epilog: PV(last) ==============================
  asm volatile("s_waitcnt vmcnt(0)" ::: "memory");
  __builtin_amdgcn_sched_barrier(0);
  {
    int vb = (STEPS - 1) & 1;
    const short* vf0 = vb ? vfB0 : vfA0;
    const short* vf1 = vb ? vfB1 : vfA1;
    bf16x8 vf[4];
#pragma unroll
    for (int i = 0; i < 4; ++i) vf[i] = *(const bf16x8*)(vf0 + i * 1024);
#pragma unroll
    for (int j = 0; j < 4; ++j) {
      bf16x8 pf = *(const bf16x8*)(pfr0 + j * 1024);
#pragma unroll
      for (int i = 0; i < 4; ++i) acc[i][j] = mfma16(vf[i], pf, acc[i][j]);
    }
#pragma unroll
    for (int i = 0; i < 4; ++i) vf[i] = *(const bf16x8*)(vf1 + i * 1024);
#pragma unroll
    for (int j = 0; j < 4; ++j) {
      bf16x8 pf = *(const bf16x8*)(pfr1 + j * 1024);
#pragma unroll
      for (int i = 0; i < 4; ++i) acc[i][j] = mfma16(vf[i], pf, acc[i][j]);
    }
  }

  // l reduce: per-kqh-half partials
  lp += __shfl_xor(lp, 16);
  lp += __shfl_xor(lp, 32);
  if (g == 0) lsum2[kqh][qrow] = lp;
  LGKM0_BAR();

  float* out_b = out + (size_t)b * N * DK;
#pragma unroll
  for (int j = 0; j < 4; ++j) {
    int qq = vh * 64 + j * 16 + c;
    float rl = 1.f / (lsum2[0][qq] + lsum2[1][qq]);
    int q = q0 + qq;
#pragma unroll
    for (int i = 0; i < 4; ++i) {
      f32x4 o = acc[i][j];
      o[0] *= rl; o[1] *= rl; o[2] *= rl; o[3] *= rl;
      *(f32x4*)&out_b[(size_t)q * DK + vs * 64 + i * 16 + g * 4] = o;
    }
  }
}

// ---------------------------------------------------------------------------
extern "C" void kernel_launch(void* const* d_in, const int* in_sizes, int n_in,
                              void* d_out, int out_size, void* d_ws, size_t ws_size,
                              hipStream_t stream) {
  (void)in_sizes; (void)n_in; (void)out_size; (void)ws_size;
  const float* K  = (const float*)d_in[0];
  const float* Q  = (const float*)d_in[1];
  const float* V  = (const float*)d_in[2];
  const float* Wk = (const float*)d_in[3];
  const float* bk = (const float*)d_in[4];
  const float* Wq = (const float*)d_in[5];
  const float* bq = (const float*)d_in[6];
  float* out = (float*)d_out;

  char* ws = (char*)d_ws;
  short* pq  = (short*)(ws + 0);
  short* pk  = (short*)(ws + ((size_t)4 << 20));
  short* vt  = (short*)(ws + ((size_t)8 << 20));
  short* WqB = (short*)(ws + ((size_t)40 << 20));
  short* WkB = (short*)(ws + ((size_t)40 << 20) + 64 * 512 * 2);

  hipLaunchKernelGGL(wconv_kernel,  dim3(128),  dim3(256), 0, stream, Wk, Wq, WkB, WqB);
  hipLaunchKernelGGL(vtrans_kernel, dim3(4096), dim3(256), 0, stream, V, vt);
  hipLaunchKernelGGL(proj_kernel,   dim3(512),  dim3(512), 0, stream, Q, K, WqB, WkB, bq, bk, pq, pk);
  hipLaunchKernelGGL(flash_kernel,  dim3(256),  dim3(1024), 0, stream, pq, pk, vt, out);
}